// Round 3
// baseline (706.467 us; speedup 1.0000x reference)
//
#include <hip/hip_runtime.h>
#include <hip/hip_bf16.h>
#include <cstdint>

// GroupFNO1d on MI355X. Rows = B*E = 32768.
// Spectral layer (64 kept rFFT modes) == analysis GEMM (N=128 cos/-sin rows) +
// per-(e,k) complex mix + synthesis folded into next weight matrix (K 1024->1152).
// Net = 3 big bf16 GEMMs (256^2 tile, counted-vmcnt pipeline) + 2 skinny mix GEMMs
// (128^2 kernel) + fused fc tail. Workspace ws_size-adaptive, chunked by rows (x256).

typedef __bf16 bf16;
typedef __attribute__((ext_vector_type(8))) __bf16 bf16x8;
typedef __attribute__((ext_vector_type(4))) float f32x4;

#define N_ROWS 32768

__device__ __forceinline__ void gl_lds16(const void* g, void* l) {
    __builtin_amdgcn_global_load_lds(
        (const __attribute__((address_space(1))) void*)g,
        (__attribute__((address_space(3))) void*)l,
        16, 0, 0);
}

__device__ __forceinline__ float swishf(float v) {
    return v / (1.f + __expf(-v));
}

// ---------------- setup kernels ----------------

__global__ __launch_bounds__(256) void build_cmix(const float* __restrict__ codes,
                                                  const float* __restrict__ com,
                                                  const float* __restrict__ code,
                                                  const float* __restrict__ filt,
                                                  float2* __restrict__ cmix) {
    int t = blockIdx.x * 256 + threadIdx.x;
    if (t >= 16 * 64) return;
    int e = t >> 6, m = t & 63;
    float er = 0.f, ei = 0.f;
    for (int c = 0; c < 64; ++c) {
        float cd = codes[e * 64 + c];
        er += cd * code[(c * 64 + m) * 2 + 0];
        ei += cd * code[(c * 64 + m) * 2 + 1];
    }
    float f = filt[m];
    float lam = fminf(fmaxf((f + 3.f) * (1.f / 6.f), 0.f), 1.f);
    float cr = lam * com[m * 2 + 0] + (1.f - lam) * er;
    float ci = lam * com[m * 2 + 1] + (1.f - lam) * ei;
    float g = (m == 0) ? (1.f / 1024.f) : (2.f / 1024.f);
    cmix[t] = make_float2(g * cr, g * ci);
}

// Fb (128 x 1024): row 2k = cos(2*pi*k*s/1024), row 2k+1 = -sin(...)
__global__ __launch_bounds__(256) void build_fb(bf16* __restrict__ Fb) {
    int t = blockIdx.x * 256 + threadIdx.x;   // 131072
    int rr = t >> 10, s = t & 1023;
    int k = rr >> 1;
    int ph = (k * s) & 1023;
    float ang = (float)ph * 6.1359231515425649e-3f;  // 2*pi/1024
    float v = (rr & 1) ? -sinf(ang) : cosf(ang);
    Fb[t] = (bf16)v;
}

// Bcat (1024 x 1152): cols 0..1023 = w[j][c]; col 1024+2k = cos(2*pi*k*j/1024), +2k+1 = -sin
__global__ __launch_bounds__(256) void build_bcat(const float* __restrict__ w,
                                                  bf16* __restrict__ out) {
    int t = blockIdx.x * 256 + threadIdx.x;
    if (t >= 1024 * 1152) return;
    int j = t / 1152, c = t % 1152;
    float v;
    if (c < 1024) {
        v = w[j * 1024 + c];
    } else {
        int cc = c - 1024, k = cc >> 1;
        int ph = (k * j) & 1023;
        float ang = (float)ph * 6.1359231515425649e-3f;
        v = (cc & 1) ? -sinf(ang) : cosf(ang);
    }
    out[t] = (bf16)v;
}

__global__ __launch_bounds__(256) void convert_bf16(const float* __restrict__ in,
                                                    bf16* __restrict__ out, int n) {
    int t = blockIdx.x * 256 + threadIdx.x;
    if (t < n) out[t] = (bf16)in[t];
}

// A0[n][0:512] = x_chunk[n*512 + s];  A0[n][512+s] = s/511
__global__ __launch_bounds__(256) void build_a0(const float* __restrict__ x,
                                                bf16* __restrict__ A0) {
    int t = blockIdx.x * 256 + threadIdx.x;
    int n = t >> 7, part = t & 127;
    bf16x8 o;
    if (part < 64) {
        const float4* xp = (const float4*)(x + ((size_t)n * 512 + part * 8));
        float4 a = xp[0], b = xp[1];
        o[0] = (bf16)a.x; o[1] = (bf16)a.y; o[2] = (bf16)a.z; o[3] = (bf16)a.w;
        o[4] = (bf16)b.x; o[5] = (bf16)b.y; o[6] = (bf16)b.z; o[7] = (bf16)b.w;
        *(bf16x8*)(A0 + (size_t)n * 1024 + part * 8) = o;
    } else {
        int s0 = (part - 64) * 8;
        #pragma unroll
        for (int j = 0; j < 8; ++j) o[j] = (bf16)((float)(s0 + j) * (1.0f / 511.0f));
        *(bf16x8*)(A0 + (size_t)n * 1024 + 512 + s0) = o;
    }
}

// ---------------- big GEMM: 256x256 tile, counted-vmcnt pipeline ----------------
// C = A @ Bt^T (+bias)(+swish | f32 out). A (M x K) bf16 lda; Bt (N x K) bf16 ldb.
// 512 thr = 8 waves (2M x 4N), each wave 128x64 C = 8x4 frags of 16x16x32.
// BK=32, 4 LDS slots (A+B 16KB each -> 128KB), 2-deep prefetch, ONE barrier/iter,
// vmcnt(8) counted in steady state (peeled 4 -> 0 at tail).
// Safety: stage(t+2) targets slot (t-2)&3 whose ds_reads finished (lgkmcnt(0))
// before barrier(t-1), which all waves passed before any wave issues stage(t+2).
template<int ACT, int OUTF32>
__global__ __launch_bounds__(512, 2)
void gemm256(const bf16* __restrict__ A, int lda,
             const bf16* __restrict__ Bt, int ldb,
             const float* __restrict__ bias,
             void* __restrict__ Cout, int ldc,
             int K) {
    __shared__ bf16 sA[4][256 * 32];
    __shared__ bf16 sB[4][256 * 32];
    const int tid = threadIdx.x;
    const int wave = tid >> 6, lane = tid & 63;
    const int wm = wave >> 2, wn = wave & 3;
    const int rowA0 = blockIdx.x * 256;
    const int rowB0 = blockIdx.y * 256;

    f32x4 acc[8][4];
    #pragma unroll
    for (int m = 0; m < 8; ++m)
        #pragma unroll
        for (int n = 0; n < 4; ++n)
            acc[m][n] = f32x4{0.f, 0.f, 0.f, 0.f};

    // staging: per gl_lds a wave covers 16 rows x 32 cols (lane -> row lane>>2, col (lane&3)*8)
    const int sr = wave * 16 + (lane >> 2);
    const int sc = (lane & 3) * 8;
    const bf16* gA0 = A + (size_t)(rowA0 + sr) * lda + sc;
    const bf16* gA1 = A + (size_t)(rowA0 + 128 + sr) * lda + sc;
    const bf16* gB0 = Bt + (size_t)(rowB0 + sr) * ldb + sc;
    const bf16* gB1 = Bt + (size_t)(rowB0 + 128 + sr) * ldb + sc;
    const int lo0 = (wave * 16) * 32;          // wave-uniform LDS element offsets
    const int lo1 = (128 + wave * 16) * 32;

    const int NT = K / 32;
    auto STAGE = [&](int t) {
        const int slot = t & 3;
        const size_t ko = (size_t)t * 32;
        gl_lds16(gA0 + ko, &sA[slot][lo0]);
        gl_lds16(gA1 + ko, &sA[slot][lo1]);
        gl_lds16(gB0 + ko, &sB[slot][lo0]);
        gl_lds16(gB1 + ko, &sB[slot][lo1]);
    };

    STAGE(0);
    STAGE(1);

    const int abase = (wm * 128 + (lane & 15)) * 32 + (lane >> 4) * 8;
    const int bbase = (wn * 64 + (lane & 15)) * 32 + (lane >> 4) * 8;

    for (int t = 0; t < NT; ++t) {
        if (t + 2 < NT) STAGE(t + 2);
        if (t < NT - 2)       { asm volatile("s_waitcnt vmcnt(8)" ::: "memory"); }
        else if (t == NT - 2) { asm volatile("s_waitcnt vmcnt(4)" ::: "memory"); }
        else                  { asm volatile("s_waitcnt vmcnt(0)" ::: "memory"); }
        __builtin_amdgcn_s_barrier();
        __builtin_amdgcn_sched_barrier(0);
        const bf16* sa = &sA[t & 3][abase];
        const bf16* sb = &sB[t & 3][bbase];
        bf16x8 af[8], bfr[4];
        #pragma unroll
        for (int m = 0; m < 8; ++m) af[m] = *(const bf16x8*)(sa + m * 16 * 32);
        #pragma unroll
        for (int n = 0; n < 4; ++n) bfr[n] = *(const bf16x8*)(sb + n * 16 * 32);
        asm volatile("s_waitcnt lgkmcnt(0)" ::: "memory");
        __builtin_amdgcn_sched_barrier(0);
        __builtin_amdgcn_s_setprio(1);
        #pragma unroll
        for (int m = 0; m < 8; ++m)
            #pragma unroll
            for (int n = 0; n < 4; ++n)
                acc[m][n] = __builtin_amdgcn_mfma_f32_16x16x32_bf16(af[m], bfr[n], acc[m][n], 0, 0, 0);
        __builtin_amdgcn_s_setprio(0);
        __builtin_amdgcn_sched_barrier(0);
    }

    const int rowb = rowA0 + wm * 128;
    const int colb = rowB0 + wn * 64;
    #pragma unroll
    for (int m = 0; m < 8; ++m) {
        #pragma unroll
        for (int n = 0; n < 4; ++n) {
            int col = colb + n * 16 + (lane & 15);
            float bv = bias ? bias[col] : 0.f;
            #pragma unroll
            for (int r = 0; r < 4; ++r) {
                int row = rowb + m * 16 + (lane >> 4) * 4 + r;
                float v = acc[m][n][r] + bv;
                if (ACT) v = swishf(v);
                if (OUTF32) ((float*)Cout)[(size_t)row * ldc + col] = v;
                else        ((bf16*)Cout)[(size_t)row * ldc + col] = (bf16)v;
            }
        }
    }
}

// ---------------- 128^2 GEMM (kept for the N=128 analysis+mix step) ----------------
// MIX epilogue: even col 2k = Xr, odd 2k+1 = Xi; Ymix[2k]=Xr*cr-Xi*ci, [2k+1]=Xr*ci+Xi*cr.
__global__ __launch_bounds__(256)
void gemm_mix(const bf16* __restrict__ A, int lda,
              const bf16* __restrict__ Bt, int ldb,
              void* __restrict__ Cout, int ldc,
              const float2* __restrict__ cmix,
              int K) {
    __shared__ bf16 sA[128 * 64];
    __shared__ bf16 sB[128 * 64];
    const int tid = threadIdx.x;
    const int wave = tid >> 6;
    const int lane = tid & 63;
    const int wm = wave >> 1, wn = wave & 1;
    const int rowA0 = blockIdx.x * 128;
    const int rowB0 = 0;

    f32x4 acc[4][4];
    #pragma unroll
    for (int m = 0; m < 4; ++m)
        #pragma unroll
        for (int n = 0; n < 4; ++n)
            acc[m][n] = f32x4{0.f, 0.f, 0.f, 0.f};

    const int srow = wave * 32 + (lane >> 3);
    const int scol = (lane & 7) * 8;
    const bf16* gA = A + (size_t)(rowA0 + srow) * lda + scol;
    const bf16* gB = Bt + (size_t)(rowB0 + srow) * ldb + scol;
    bf16* lA = &sA[(wave * 32) * 64];
    bf16* lB = &sB[(wave * 32) * 64];

    for (int k0 = 0; k0 < K; k0 += 64) {
        __syncthreads();
        #pragma unroll
        for (int i = 0; i < 4; ++i) {
            gl_lds16(gA + (size_t)i * 8 * lda + k0, lA + i * 8 * 64);
            gl_lds16(gB + (size_t)i * 8 * ldb + k0, lB + i * 8 * 64);
        }
        __syncthreads();
        #pragma unroll
        for (int kk = 0; kk < 64; kk += 32) {
            bf16x8 af[4], bfr[4];
            #pragma unroll
            for (int m = 0; m < 4; ++m)
                af[m] = *(const bf16x8*)&sA[(wm * 64 + m * 16 + (lane & 15)) * 64 + kk + ((lane >> 4) * 8)];
            #pragma unroll
            for (int n = 0; n < 4; ++n)
                bfr[n] = *(const bf16x8*)&sB[(wn * 64 + n * 16 + (lane & 15)) * 64 + kk + ((lane >> 4) * 8)];
            #pragma unroll
            for (int m = 0; m < 4; ++m)
                #pragma unroll
                for (int n = 0; n < 4; ++n)
                    acc[m][n] = __builtin_amdgcn_mfma_f32_16x16x32_bf16(af[m], bfr[n], acc[m][n], 0, 0, 0);
        }
    }

    const int rowb = rowA0 + wm * 64;
    #pragma unroll
    for (int m = 0; m < 4; ++m) {
        #pragma unroll
        for (int n = 0; n < 4; ++n) {
            int col = wn * 64 + n * 16 + (lane & 15);   // 0..127, parity == lane parity
            int k = col >> 1;
            #pragma unroll
            for (int r = 0; r < 4; ++r) {
                float v = acc[m][n][r];
                float p = __shfl_xor(v, 1);
                int row = rowb + m * 16 + (lane >> 4) * 4 + r;
                float2 c = cmix[(row & 15) * 64 + k];
                float val = v * c.x + (((lane & 1) == 0) ? -p * c.y : p * c.y);
                ((bf16*)Cout)[(size_t)row * ldc + col] = (bf16)val;
            }
        }
    }
}

// ---------------- fused fc1 + swish + fc2 ----------------
__global__ __launch_bounds__(256) void fc_fused(const float* __restrict__ H,
                                                const float* __restrict__ w1,
                                                const float* __restrict__ b1,
                                                const float* __restrict__ w2,
                                                const float* __restrict__ b2,
                                                float* __restrict__ out) {
    __shared__ float sw2[8][2048];
    __shared__ float ss[2048];
    int tid = threadIdx.x;
    for (int i = tid; i < 8 * 2048; i += 256) sw2[i >> 11][i & 2047] = w2[i];

    float wv[16];
    const float4* w1p = (const float4*)(w1 + tid * 16);
    *(float4*)&wv[0]  = w1p[0];
    *(float4*)&wv[4]  = w1p[1];
    *(float4*)&wv[8]  = w1p[2];
    *(float4*)&wv[12] = w1p[3];
    float bb[8];
    const float4* b1p = (const float4*)(b1 + tid * 8);
    *(float4*)&bb[0] = b1p[0];
    *(float4*)&bb[4] = b1p[1];
    __syncthreads();

    for (int r = 0; r < 16; ++r) {
        int n = blockIdx.x * 16 + r;
        const float* h = H + (size_t)n * 1024;
        float4 hv = *(const float4*)(h + tid * 4);
        float hh[4] = {hv.x, hv.y, hv.z, hv.w};
        #pragma unroll
        for (int jj = 0; jj < 8; ++jj) {
            float h0 = hh[(jj >> 2) * 2];
            float h1 = hh[(jj >> 2) * 2 + 1];
            float t = h0 * wv[2 * jj] + h1 * wv[2 * jj + 1] + bb[jj];
            ss[tid * 8 + jj] = swishf(t);
        }
        __syncthreads();
        int o8 = tid >> 5, l5 = tid & 31;
        float p = 0.f;
        #pragma unroll 8
        for (int i = 0; i < 64; ++i) {
            int j = l5 + 32 * i;
            p += ss[j] * sw2[o8][j];
        }
        #pragma unroll
        for (int msk = 1; msk < 32; msk <<= 1) p += __shfl_xor(p, msk);
        if (l5 == 0) out[(size_t)n * 8 + o8] = p + b2[o8];
        __syncthreads();
    }
}

// ---------------- launch ----------------

extern "C" void kernel_launch(void* const* d_in, const int* in_sizes, int n_in,
                              void* d_out, int out_size, void* d_ws, size_t ws_size,
                              hipStream_t stream) {
    const float* x     = (const float*)d_in[0];
    const float* codes = (const float*)d_in[1];
    const float* p_w   = (const float*)d_in[2];
    const float* p_b   = (const float*)d_in[3];
    const float* com0  = (const float*)d_in[4];
    const float* code0 = (const float*)d_in[5];
    const float* filt0 = (const float*)d_in[6];
    const float* com1  = (const float*)d_in[7];
    const float* code1 = (const float*)d_in[8];
    const float* filt1 = (const float*)d_in[9];
    const float* w0_w  = (const float*)d_in[10];
    const float* w0_b  = (const float*)d_in[11];
    const float* w1_w  = (const float*)d_in[12];
    const float* w1_b  = (const float*)d_in[13];
    const float* fc1w  = (const float*)d_in[14];
    const float* fc1b  = (const float*)d_in[15];
    const float* fc2w  = (const float*)d_in[16];
    const float* fc2b  = (const float*)d_in[17];
    float* out = (float*)d_out;

    // fixed weight region (~6.77 MB)
    char* ws = (char*)d_ws;
    bf16*  pwb  = (bf16*)(ws + 0);               // 2,097,152
    bf16*  B0   = (bf16*)(ws + 2097152);         // 2,359,296
    bf16*  B1   = (bf16*)(ws + 4456448);         // 2,359,296
    bf16*  Fb   = (bf16*)(ws + 6815744);         // 262,144
    float2* cm0 = (float2*)(ws + 7077888);       // 8,192
    float2* cm1 = (float2*)(ws + 7086080);       // 8,192
    const size_t CB = 7094272;

    // row-chunk size R (multiple of 256)
    const size_t PER_ROW = 4096 + 2304 + 2304;   // AH region (max(A0,H3)) + A1cat + A2cat
    long rmax = 0;
    if (ws_size > CB) rmax = (long)((ws_size - CB) / PER_ROW) / 256 * 256;
    if (rmax > N_ROWS) rmax = N_ROWS;            // single chunk if workspace allows (~292MB)
    if (rmax < 256) {
        hipMemsetAsync(d_out, 0, (size_t)out_size * sizeof(float), stream);
        return;
    }
    const int R = (int)rmax;

    build_cmix<<<4, 256, 0, stream>>>(codes, com0, code0, filt0, cm0);
    build_cmix<<<4, 256, 0, stream>>>(codes, com1, code1, filt1, cm1);
    build_fb<<<512, 256, 0, stream>>>(Fb);
    build_bcat<<<4608, 256, 0, stream>>>(w0_w, B0);
    build_bcat<<<4608, 256, 0, stream>>>(w1_w, B1);
    convert_bf16<<<4096, 256, 0, stream>>>(p_w, pwb, 1024 * 1024);

    char* cb = ws + CB;
    for (int row0 = 0; row0 < N_ROWS; row0 += R) {
        const int r = (N_ROWS - row0 < R) ? (N_ROWS - row0) : R;   // multiple of 256
        bf16*  A0 = (bf16*)cb;
        float* H3 = (float*)cb;                                    // reuses A0 region
        bf16*  A1 = (bf16*)(cb + (size_t)R * 4096);
        bf16*  A2 = (bf16*)(cb + (size_t)R * 4096 + (size_t)R * 2304);

        build_a0<<<r / 2, 256, 0, stream>>>(x + (size_t)row0 * 512, A0);

        // h1 = A0 @ p_w^T + p_b -> A1cat[:,0:1024]
        gemm256<0, 0><<<dim3(r / 256, 4), 512, 0, stream>>>(
            A0, 1024, pwb, 1024, p_b, (void*)A1, 1152, 1024);
        // Ymix0 -> A1cat[:,1024:1152]
        gemm_mix<<<dim3(r / 128, 1), 256, 0, stream>>>(
            A1, 1152, Fb, 1024, (void*)(A1 + 1024), 1152, cm0, 1024);
        // h2 = swish(A1cat @ Bcat0^T + w0_b) -> A2cat[:,0:1024]
        gemm256<1, 0><<<dim3(r / 256, 4), 512, 0, stream>>>(
            A1, 1152, B0, 1152, w0_b, (void*)A2, 1152, 1152);
        // Ymix1 -> A2cat[:,1024:1152]
        gemm_mix<<<dim3(r / 128, 1), 256, 0, stream>>>(
            A2, 1152, Fb, 1024, (void*)(A2 + 1024), 1152, cm1, 1024);
        // H3 = A2cat @ Bcat1^T + w1_b (f32)
        gemm256<0, 1><<<dim3(r / 256, 4), 512, 0, stream>>>(
            A2, 1152, B1, 1152, w1_b, (void*)H3, 1024, 1152);
        // out = fc2(swish(fc1(H3)))
        fc_fused<<<r / 16, 256, 0, stream>>>(H3, fc1w, fc1b, fc2w, fc2b, out + (size_t)row0 * 8);
    }
}

// Round 4
// 467.610 us; speedup vs baseline: 1.5108x; 1.5108x over previous
//
#include <hip/hip_runtime.h>
#include <hip/hip_bf16.h>
#include <cstdint>

// GroupFNO1d on MI355X. Rows = B*E = 32768.
// Spectral layer (64 kept rFFT modes) == analysis GEMM (N=128 cos/-sin rows) +
// per-(e,k) complex mix + synthesis folded into next weight matrix (K 1024->1152).
// Net = 3 big bf16 GEMMs (256^2 tile, BK=64, T2-swizzled LDS, counted pipeline) +
// 2 skinny mix GEMMs + fused bf16 fc tail. Workspace ws_size-adaptive.

typedef __bf16 bf16;
typedef __attribute__((ext_vector_type(8))) __bf16 bf16x8;
typedef __attribute__((ext_vector_type(4))) __bf16 bf16x4;
typedef __attribute__((ext_vector_type(4))) float f32x4;

#define N_ROWS 32768

__device__ __forceinline__ void gl_lds16(const void* g, void* l) {
    __builtin_amdgcn_global_load_lds(
        (const __attribute__((address_space(1))) void*)g,
        (__attribute__((address_space(3))) void*)l,
        16, 0, 0);
}

__device__ __forceinline__ float swishf(float v) {
    return v / (1.f + __expf(-v));
}

// ---------------- setup kernels ----------------

__global__ __launch_bounds__(256) void build_cmix(const float* __restrict__ codes,
                                                  const float* __restrict__ com,
                                                  const float* __restrict__ code,
                                                  const float* __restrict__ filt,
                                                  float2* __restrict__ cmix) {
    int t = blockIdx.x * 256 + threadIdx.x;
    if (t >= 16 * 64) return;
    int e = t >> 6, m = t & 63;
    float er = 0.f, ei = 0.f;
    for (int c = 0; c < 64; ++c) {
        float cd = codes[e * 64 + c];
        er += cd * code[(c * 64 + m) * 2 + 0];
        ei += cd * code[(c * 64 + m) * 2 + 1];
    }
    float f = filt[m];
    float lam = fminf(fmaxf((f + 3.f) * (1.f / 6.f), 0.f), 1.f);
    float cr = lam * com[m * 2 + 0] + (1.f - lam) * er;
    float ci = lam * com[m * 2 + 1] + (1.f - lam) * ei;
    float g = (m == 0) ? (1.f / 1024.f) : (2.f / 1024.f);
    cmix[t] = make_float2(g * cr, g * ci);
}

// Fb (128 x 1024): row 2k = cos(2*pi*k*s/1024), row 2k+1 = -sin(...)
__global__ __launch_bounds__(256) void build_fb(bf16* __restrict__ Fb) {
    int t = blockIdx.x * 256 + threadIdx.x;   // 131072
    int rr = t >> 10, s = t & 1023;
    int k = rr >> 1;
    int ph = (k * s) & 1023;
    float ang = (float)ph * 6.1359231515425649e-3f;  // 2*pi/1024
    float v = (rr & 1) ? -sinf(ang) : cosf(ang);
    Fb[t] = (bf16)v;
}

// Bcat (1024 x 1152): cols 0..1023 = w[j][c]; col 1024+2k = cos(2*pi*k*j/1024), +2k+1 = -sin
__global__ __launch_bounds__(256) void build_bcat(const float* __restrict__ w,
                                                  bf16* __restrict__ out) {
    int t = blockIdx.x * 256 + threadIdx.x;
    if (t >= 1024 * 1152) return;
    int j = t / 1152, c = t % 1152;
    float v;
    if (c < 1024) {
        v = w[j * 1024 + c];
    } else {
        int cc = c - 1024, k = cc >> 1;
        int ph = (k * j) & 1023;
        float ang = (float)ph * 6.1359231515425649e-3f;
        v = (cc & 1) ? -sinf(ang) : cosf(ang);
    }
    out[t] = (bf16)v;
}

__global__ __launch_bounds__(256) void convert_bf16(const float* __restrict__ in,
                                                    bf16* __restrict__ out, int n) {
    int t = blockIdx.x * 256 + threadIdx.x;
    if (t < n) out[t] = (bf16)in[t];
}

// A0[n][0:512] = x_chunk[n*512 + s];  A0[n][512+s] = s/511
__global__ __launch_bounds__(256) void build_a0(const float* __restrict__ x,
                                                bf16* __restrict__ A0) {
    int t = blockIdx.x * 256 + threadIdx.x;
    int n = t >> 7, part = t & 127;
    bf16x8 o;
    if (part < 64) {
        const float4* xp = (const float4*)(x + ((size_t)n * 512 + part * 8));
        float4 a = xp[0], b = xp[1];
        o[0] = (bf16)a.x; o[1] = (bf16)a.y; o[2] = (bf16)a.z; o[3] = (bf16)a.w;
        o[4] = (bf16)b.x; o[5] = (bf16)b.y; o[6] = (bf16)b.z; o[7] = (bf16)b.w;
        *(bf16x8*)(A0 + (size_t)n * 1024 + part * 8) = o;
    } else {
        int s0 = (part - 64) * 8;
        #pragma unroll
        for (int j = 0; j < 8; ++j) o[j] = (bf16)((float)(s0 + j) * (1.0f / 511.0f));
        *(bf16x8*)(A0 + (size_t)n * 1024 + 512 + s0) = o;
    }
}

// ---------------- big GEMM: 256x256 tile, BK=64, T2 swizzle, 1 barrier/iter --------
// C = A @ Bt^T + bias (+swish), bf16 out. 512 thr = 8 waves (2M x 4N), per-wave
// 128x64 C = 8x4 frags of 16x16x32. LDS [2 slots][256][64] bf16 per matrix (128KB).
// T2 swizzle per rule #21: gl_lds writes LINEAR; the per-lane GLOBAL source takes
// col-slot (l&7)^(l>>3); reads XOR byte addr with ((p&7)<<4). row&7 == p&7 always
// (all row offsets are multiples of 8/16), so one involution both sides.
// Pipeline per iter t: vmcnt(0) [drains only STAGE(t), STAGE(t+1) not yet issued]
// -> barrier -> STAGE(t+1) (8 gl_lds, lands during this iter's 64 MFMA) -> reads ->
// lgkmcnt(0) -> MFMA. Slot (t+1)&1 was last read at iter t-1, all waves passed
// barrier(t) after finishing those reads (lgkmcnt(0) precedes their MFMA) -> safe.
template<int ACT>
__global__ __launch_bounds__(512, 2)
void gemm256(const bf16* __restrict__ A, int lda,
             const bf16* __restrict__ Bt, int ldb,
             const float* __restrict__ bias,
             bf16* __restrict__ Cout, int ldc,
             int K) {
    __shared__ bf16 sA[2][256 * 64];
    __shared__ bf16 sB[2][256 * 64];
    const int tid = threadIdx.x;
    const int wave = tid >> 6, lane = tid & 63;
    const int wm = wave >> 2, wn = wave & 3;
    const int rowA0 = blockIdx.x * 256;
    const int rowB0 = blockIdx.y * 256;

    f32x4 acc[8][4];
    #pragma unroll
    for (int m = 0; m < 8; ++m)
        #pragma unroll
        for (int n = 0; n < 4; ++n)
            acc[m][n] = f32x4{0.f, 0.f, 0.f, 0.f};

    // staging: per gl_lds the wave covers 8 rows x 64 cols (1024B). lane l ->
    // row l>>3, col-slot (l&7)^(l>>3) (inverse swizzle on the global side).
    const int srq = lane >> 3;                 // 0..7 row within 8-row group
    const int ssl = (lane & 7) ^ srq;          // swizzled 16B col slot
    const bf16* gA = A + (size_t)(rowA0 + wave * 8 + srq) * lda + ssl * 8;
    const bf16* gB = Bt + (size_t)(rowB0 + wave * 8 + srq) * ldb + ssl * 8;

    const int NT = K / 64;
    auto STAGE = [&](int t) {
        const int slot = t & 1;
        const size_t ko = (size_t)t * 64;
        #pragma unroll
        for (int j = 0; j < 4; ++j) {
            gl_lds16(gA + (size_t)j * 64 * lda + ko, &sA[slot][(j * 64 + wave * 8) * 64]);
            gl_lds16(gB + (size_t)j * 64 * ldb + ko, &sB[slot][(j * 64 + wave * 8) * 64]);
        }
    };

    STAGE(0);

    const int p = lane & 15, q = lane >> 4;
    const int axr = (p & 7) << 4;              // read-side byte XOR

    for (int t = 0; t < NT; ++t) {
        asm volatile("s_waitcnt vmcnt(0)" ::: "memory");
        __builtin_amdgcn_s_barrier();
        __builtin_amdgcn_sched_barrier(0);
        if (t + 1 < NT) STAGE(t + 1);
        const char* sa = (const char*)sA[t & 1];
        const char* sb = (const char*)sB[t & 1];
        #pragma unroll
        for (int kk = 0; kk < 64; kk += 32) {
            bf16x8 af[8], bfr[4];
            #pragma unroll
            for (int m = 0; m < 8; ++m) {
                int off = (((wm * 128 + m * 16 + p) * 64 + kk + q * 8) * 2) ^ axr;
                af[m] = *(const bf16x8*)(sa + off);
            }
            #pragma unroll
            for (int n = 0; n < 4; ++n) {
                int off = (((wn * 64 + n * 16 + p) * 64 + kk + q * 8) * 2) ^ axr;
                bfr[n] = *(const bf16x8*)(sb + off);
            }
            asm volatile("s_waitcnt lgkmcnt(0)" ::: "memory");
            __builtin_amdgcn_sched_barrier(0);
            __builtin_amdgcn_s_setprio(1);
            #pragma unroll
            for (int m = 0; m < 8; ++m)
                #pragma unroll
                for (int n = 0; n < 4; ++n)
                    acc[m][n] = __builtin_amdgcn_mfma_f32_16x16x32_bf16(af[m], bfr[n], acc[m][n], 0, 0, 0);
            __builtin_amdgcn_s_setprio(0);
            __builtin_amdgcn_sched_barrier(0);
        }
    }

    const int rowb = rowA0 + wm * 128;
    const int colb = rowB0 + wn * 64;
    #pragma unroll
    for (int m = 0; m < 8; ++m) {
        #pragma unroll
        for (int n = 0; n < 4; ++n) {
            int col = colb + n * 16 + p;
            float bv = bias ? bias[col] : 0.f;
            #pragma unroll
            for (int r = 0; r < 4; ++r) {
                int row = rowb + m * 16 + q * 4 + r;
                float v = acc[m][n][r] + bv;
                if (ACT) v = swishf(v);
                Cout[(size_t)row * ldc + col] = (bf16)v;
            }
        }
    }
}

// ---------------- 128^2 GEMM for the N=128 analysis+mix step ----------------
// MIX epilogue: even col 2k = Xr, odd 2k+1 = Xi; Ymix[2k]=Xr*cr-Xi*ci, [2k+1]=Xr*ci+Xi*cr.
__global__ __launch_bounds__(256)
void gemm_mix(const bf16* __restrict__ A, int lda,
              const bf16* __restrict__ Bt, int ldb,
              void* __restrict__ Cout, int ldc,
              const float2* __restrict__ cmix,
              int K) {
    __shared__ bf16 sA[128 * 64];
    __shared__ bf16 sB[128 * 64];
    const int tid = threadIdx.x;
    const int wave = tid >> 6;
    const int lane = tid & 63;
    const int wm = wave >> 1, wn = wave & 1;
    const int rowA0 = blockIdx.x * 128;

    f32x4 acc[4][4];
    #pragma unroll
    for (int m = 0; m < 4; ++m)
        #pragma unroll
        for (int n = 0; n < 4; ++n)
            acc[m][n] = f32x4{0.f, 0.f, 0.f, 0.f};

    const int srow = wave * 32 + (lane >> 3);
    const int scol = (lane & 7) * 8;
    const bf16* gA = A + (size_t)(rowA0 + srow) * lda + scol;
    const bf16* gB = Bt + (size_t)srow * ldb + scol;
    bf16* lA = &sA[(wave * 32) * 64];
    bf16* lB = &sB[(wave * 32) * 64];

    for (int k0 = 0; k0 < K; k0 += 64) {
        __syncthreads();
        #pragma unroll
        for (int i = 0; i < 4; ++i) {
            gl_lds16(gA + (size_t)i * 8 * lda + k0, lA + i * 8 * 64);
            gl_lds16(gB + (size_t)i * 8 * ldb + k0, lB + i * 8 * 64);
        }
        __syncthreads();
        #pragma unroll
        for (int kk = 0; kk < 64; kk += 32) {
            bf16x8 af[4], bfr[4];
            #pragma unroll
            for (int m = 0; m < 4; ++m)
                af[m] = *(const bf16x8*)&sA[(wm * 64 + m * 16 + (lane & 15)) * 64 + kk + ((lane >> 4) * 8)];
            #pragma unroll
            for (int n = 0; n < 4; ++n)
                bfr[n] = *(const bf16x8*)&sB[(wn * 64 + n * 16 + (lane & 15)) * 64 + kk + ((lane >> 4) * 8)];
            #pragma unroll
            for (int m = 0; m < 4; ++m)
                #pragma unroll
                for (int n = 0; n < 4; ++n)
                    acc[m][n] = __builtin_amdgcn_mfma_f32_16x16x32_bf16(af[m], bfr[n], acc[m][n], 0, 0, 0);
        }
    }

    const int rowb = rowA0 + wm * 64;
    #pragma unroll
    for (int m = 0; m < 4; ++m) {
        #pragma unroll
        for (int n = 0; n < 4; ++n) {
            int col = wn * 64 + n * 16 + (lane & 15);   // 0..127, parity == lane parity
            int k = col >> 1;
            #pragma unroll
            for (int r = 0; r < 4; ++r) {
                float v = acc[m][n][r];
                float pp = __shfl_xor(v, 1);
                int row = rowb + m * 16 + (lane >> 4) * 4 + r;
                float2 c = cmix[(row & 15) * 64 + k];
                float val = v * c.x + (((lane & 1) == 0) ? -pp * c.y : pp * c.y);
                ((bf16*)Cout)[(size_t)row * ldc + col] = (bf16)val;
            }
        }
    }
}

// ---------------- fused fc1 + swish + fc2 (bf16 H, bf16 LDS) ----------------
// H (rows x 1024 bf16). Block: sw2 bf16 8x2048 (32KB) + ss bf16 2048 (4KB) ->
// 4 blocks/CU. 16 rows/block. Phase1: thread t computes s[8] for j in [8t,8t+8)
// (cols 4t..4t+4), stores one bf16x8. Phase2: (o8=tid>>5,l5=tid&31) bf16x4 strided
// dot (j = 4*l5 + 128*i), lanes hit distinct bank pairs -> ~conflict-free.
__global__ __launch_bounds__(256) void fc_fused(const bf16* __restrict__ H,
                                                const float* __restrict__ w1,
                                                const float* __restrict__ b1,
                                                const float* __restrict__ w2,
                                                const float* __restrict__ b2,
                                                float* __restrict__ out) {
    __shared__ bf16 sw2[8][2048];
    __shared__ bf16 ss[2048];
    int tid = threadIdx.x;
    for (int i = tid * 4; i < 8 * 2048; i += 1024) {
        float4 v = *(const float4*)(w2 + i);
        bf16x4 b = {(bf16)v.x, (bf16)v.y, (bf16)v.z, (bf16)v.w};
        *(bf16x4*)&sw2[0][i] = b;
    }

    float wv[16];
    const float4* w1p = (const float4*)(w1 + tid * 16);
    *(float4*)&wv[0]  = w1p[0];
    *(float4*)&wv[4]  = w1p[1];
    *(float4*)&wv[8]  = w1p[2];
    *(float4*)&wv[12] = w1p[3];
    float bb[8];
    const float4* b1p = (const float4*)(b1 + tid * 8);
    *(float4*)&bb[0] = b1p[0];
    *(float4*)&bb[4] = b1p[1];
    __syncthreads();

    for (int r = 0; r < 16; ++r) {
        int n = blockIdx.x * 16 + r;
        bf16x4 hv = *(const bf16x4*)(H + (size_t)n * 1024 + tid * 4);
        float hh[4] = {(float)hv[0], (float)hv[1], (float)hv[2], (float)hv[3]};
        bf16x8 sb;
        #pragma unroll
        for (int jj = 0; jj < 8; ++jj) {
            float h0 = hh[(jj >> 2) * 2];
            float h1 = hh[(jj >> 2) * 2 + 1];
            float t = h0 * wv[2 * jj] + h1 * wv[2 * jj + 1] + bb[jj];
            sb[jj] = (bf16)swishf(t);
        }
        *(bf16x8*)&ss[tid * 8] = sb;
        __syncthreads();
        int o8 = tid >> 5, l5 = tid & 31;
        float p = 0.f;
        #pragma unroll
        for (int i = 0; i < 16; ++i) {
            bf16x4 a = *(const bf16x4*)&ss[4 * l5 + 128 * i];
            bf16x4 b = *(const bf16x4*)&sw2[o8][4 * l5 + 128 * i];
            p += (float)a[0] * (float)b[0] + (float)a[1] * (float)b[1]
               + (float)a[2] * (float)b[2] + (float)a[3] * (float)b[3];
        }
        #pragma unroll
        for (int msk = 1; msk < 32; msk <<= 1) p += __shfl_xor(p, msk);
        if (l5 == 0) out[(size_t)n * 8 + o8] = p + b2[o8];
        __syncthreads();
    }
}

// ---------------- launch ----------------

extern "C" void kernel_launch(void* const* d_in, const int* in_sizes, int n_in,
                              void* d_out, int out_size, void* d_ws, size_t ws_size,
                              hipStream_t stream) {
    const float* x     = (const float*)d_in[0];
    const float* codes = (const float*)d_in[1];
    const float* p_w   = (const float*)d_in[2];
    const float* p_b   = (const float*)d_in[3];
    const float* com0  = (const float*)d_in[4];
    const float* code0 = (const float*)d_in[5];
    const float* filt0 = (const float*)d_in[6];
    const float* com1  = (const float*)d_in[7];
    const float* code1 = (const float*)d_in[8];
    const float* filt1 = (const float*)d_in[9];
    const float* w0_w  = (const float*)d_in[10];
    const float* w0_b  = (const float*)d_in[11];
    const float* w1_w  = (const float*)d_in[12];
    const float* w1_b  = (const float*)d_in[13];
    const float* fc1w  = (const float*)d_in[14];
    const float* fc1b  = (const float*)d_in[15];
    const float* fc2w  = (const float*)d_in[16];
    const float* fc2b  = (const float*)d_in[17];
    float* out = (float*)d_out;

    // fixed weight region (~6.77 MB)
    char* ws = (char*)d_ws;
    bf16*  pwb  = (bf16*)(ws + 0);               // 2,097,152
    bf16*  B0   = (bf16*)(ws + 2097152);         // 2,359,296
    bf16*  B1   = (bf16*)(ws + 4456448);         // 2,359,296
    bf16*  Fb   = (bf16*)(ws + 6815744);         // 262,144
    float2* cm0 = (float2*)(ws + 7077888);       // 8,192
    float2* cm1 = (float2*)(ws + 7086080);       // 8,192
    const size_t CB = 7094272;

    // row-chunk size R (multiple of 256)
    // per-row: AH region max(A0 bf16 2048, H3 bf16 2048) + A1cat 2304 + A2cat 2304
    const size_t PER_ROW = 2048 + 2304 + 2304;   // 6656
    long rmax = 0;
    if (ws_size > CB) rmax = (long)((ws_size - CB) / PER_ROW) / 256 * 256;
    if (rmax > N_ROWS) rmax = N_ROWS;            // single chunk needs ~225MB
    if (rmax < 256) {
        hipMemsetAsync(d_out, 0, (size_t)out_size * sizeof(float), stream);
        return;
    }
    const int R = (int)rmax;

    build_cmix<<<4, 256, 0, stream>>>(codes, com0, code0, filt0, cm0);
    build_cmix<<<4, 256, 0, stream>>>(codes, com1, code1, filt1, cm1);
    build_fb<<<512, 256, 0, stream>>>(Fb);
    build_bcat<<<4608, 256, 0, stream>>>(w0_w, B0);
    build_bcat<<<4608, 256, 0, stream>>>(w1_w, B1);
    convert_bf16<<<4096, 256, 0, stream>>>(p_w, pwb, 1024 * 1024);

    char* cb = ws + CB;
    for (int row0 = 0; row0 < N_ROWS; row0 += R) {
        const int r = (N_ROWS - row0 < R) ? (N_ROWS - row0) : R;   // multiple of 256
        bf16*  A0  = (bf16*)cb;
        bf16*  H3b = (bf16*)cb;                                    // reuses A0 region
        bf16*  A1  = (bf16*)(cb + (size_t)R * 2048);
        bf16*  A2  = (bf16*)(cb + (size_t)R * 2048 + (size_t)R * 2304);

        build_a0<<<r / 2, 256, 0, stream>>>(x + (size_t)row0 * 512, A0);

        // h1 = A0 @ p_w^T + p_b -> A1cat[:,0:1024]
        gemm256<0><<<dim3(r / 256, 4), 512, 0, stream>>>(
            A0, 1024, pwb, 1024, p_b, A1, 1152, 1024);
        // Ymix0 -> A1cat[:,1024:1152]
        gemm_mix<<<dim3(r / 128, 1), 256, 0, stream>>>(
            A1, 1152, Fb, 1024, (void*)(A1 + 1024), 1152, cm0, 1024);
        // h2 = swish(A1cat @ Bcat0^T + w0_b) -> A2cat[:,0:1024]
        gemm256<1><<<dim3(r / 256, 4), 512, 0, stream>>>(
            A1, 1152, B0, 1152, w0_b, A2, 1152, 1152);
        // Ymix1 -> A2cat[:,1024:1152]
        gemm_mix<<<dim3(r / 128, 1), 256, 0, stream>>>(
            A2, 1152, Fb, 1024, (void*)(A2 + 1024), 1152, cm1, 1024);
        // H3 = A2cat @ Bcat1^T + w1_b (bf16)
        gemm256<0><<<dim3(r / 256, 4), 512, 0, stream>>>(
            A2, 1152, B1, 1152, w1_b, H3b, 1024, 1152);
        // out = fc2(swish(fc1(H3)))
        fc_fused<<<r / 16, 256, 0, stream>>>(H3b, fc1w, fc1b, fc2w, fc2b, out + (size_t)row0 * 8);
    }
}